// Round 16
// baseline (92.296 us; speedup 1.0000x reference)
//
#include <hip/hip_runtime.h>
#include <hip/hip_bf16.h>

// MHA forward: B=2, S=2048, E=768, H=12, D=64.
// r10 base (89.08us passing) + k_attn kv-split: wave (qh,kh) computes q[qh*32..+32) x kv-half kh.
// Per-wave LDS fragment reads halved (8 b128/tile vs 16). Symmetric cross-wave epilogue:
// single carved LDS array, all waves write acc+l to scratch, partner (w^1) halves summed,
// wave outputs q-set n==kh. Staging/pipeline/XCD map byte-identical to r10.

typedef __bf16 bf16x8 __attribute__((ext_vector_type(8)));
typedef float f32x4 __attribute__((ext_vector_type(4)));
typedef unsigned short ushortx8 __attribute__((ext_vector_type(8)));
typedef unsigned short ushortx4 __attribute__((ext_vector_type(4)));
typedef unsigned int uintx4 __attribute__((ext_vector_type(4)));

#define EMB 768
#define SEQ 2048
#define NHEAD 12
#define HDIM 64
#define MROWS 4096
#define NQKV 2304
#define QSCALE 0.18033688011112042f   // 0.125 * log2(e)

static __device__ __forceinline__ unsigned short b16(float f) {
  __hip_bfloat16 h = __float2bfloat16(f);
  return __builtin_bit_cast(unsigned short, h);
}

// packed f32x2 -> bf16x2 (RNE); no builtin on gfx950
static __device__ __forceinline__ unsigned int cvtpk(float lo, float hi) {
  unsigned int r;
  asm("v_cvt_pk_bf16_f32 %0, %1, %2" : "=v"(r) : "v"(lo), "v"(hi));
  return r;
}

static __device__ __forceinline__ void gld16(const void* g, void* l) {
  __builtin_amdgcn_global_load_lds((const __attribute__((address_space(1))) void*)g,
                                   (__attribute__((address_space(3))) void*)l, 16, 0, 0);
}

// ---------------- fused prep: cvt(x) x8 + transpose+cvt(weights), vectorized stores ----------------
__global__ __launch_bounds__(256) void k_prep(
    const float* __restrict__ x, const float* __restrict__ wqkv, const float* __restrict__ wproj,
    unsigned short* __restrict__ xb, unsigned short* __restrict__ wqkvT,
    unsigned short* __restrict__ wprojT) {
  __shared__ float t[64][65];
  const int bid = blockIdx.x;
  const int tid = threadIdx.x;
  if (bid < 1536) {
    int i = (bid * 256 + tid) * 8;
    f32x4 v0 = *(const f32x4*)(x + i);
    f32x4 v1 = *(const f32x4*)(x + i + 4);
    ushortx8 o;
    o[0] = b16(v0[0]); o[1] = b16(v0[1]); o[2] = b16(v0[2]); o[3] = b16(v0[3]);
    o[4] = b16(v1[0]); o[5] = b16(v1[1]); o[6] = b16(v1[2]); o[7] = b16(v1[3]);
    *(ushortx8*)(xb + i) = o;
    return;
  }
  const float* in; unsigned short* out; int N, bx, by;
  if (bid < 1536 + 432) { in = wqkv;  out = wqkvT;  N = NQKV; int r = bid - 1536; bx = r % 36; by = r / 36; }
  else                  { in = wproj; out = wprojT; N = EMB;  int r = bid - 1968; bx = r % 12; by = r / 12; }
  const int n0 = bx * 64, k0 = by * 64;
  const int xx = tid & 63, y0 = tid >> 6;
  #pragma unroll
  for (int i = 0; i < 16; ++i) { int r = y0 * 16 + i; t[r][xx] = in[(size_t)(k0 + r) * N + n0 + xx]; }
  __syncthreads();
  const int ks = tid & 7;
  const int nr0 = tid >> 3;
  #pragma unroll
  for (int i = 0; i < 2; ++i) {
    int nr = nr0 + i * 32;
    ushortx8 o;
    #pragma unroll
    for (int j = 0; j < 8; ++j) o[j] = b16(t[ks * 8 + j][nr]);
    *(ushortx8*)(out + (size_t)(n0 + nr) * EMB + k0 + ks * 8) = o;
  }
}

// ---------------- 128x128 bf16 GEMM mainloop (r7-exact), BK=64, 2-buf, swizzled ----------
static __device__ __forceinline__ void gemm_tile_128(
    const unsigned short* __restrict__ A, const unsigned short* __restrict__ B,
    int K, int bm, int bn, char* lA, char* lB, f32x4 acc[4][4]) {
  const int tid = threadIdx.x, lane = tid & 63, w = tid >> 6;
  const int l15 = lane & 15, lg = lane >> 4;
  const int wm = w >> 1, wn = w & 1;
  #pragma unroll
  for (int m = 0; m < 4; ++m)
    #pragma unroll
    for (int n = 0; n < 4; ++n)
      acc[m][n] = (f32x4){0.f, 0.f, 0.f, 0.f};

  const int srow = w * 32 + (lane >> 3);
  const int glog = (lane & 7) ^ (lane >> 3);
  const size_t abase = (size_t)(bm * 128 + srow) * K + glog * 8;
  const size_t bbase = (size_t)(bn * 128 + srow) * K + glog * 8;
  const char* aB = lA + (wm * 64 + l15) * 128;
  const char* bB = lB + (wn * 64 + l15) * 128;
  const int rsw = (l15 & 7) << 4;

  const int T = K >> 6;
  {
    char* ad = lA + w * 4096; char* bd = lB + w * 4096;
    #pragma unroll
    for (int j = 0; j < 4; ++j) {
      gld16(A + abase + (size_t)j * 8 * K, ad + j * 1024);
      gld16(B + bbase + (size_t)j * 8 * K, bd + j * 1024);
    }
  }
  for (int t = 0; t < T; ++t) {
    const int cur = t & 1;
    if (t + 1 < T) {
      const int k1 = (t + 1) << 6;
      char* ad = lA + (cur ^ 1) * 16384 + w * 4096;
      char* bd = lB + (cur ^ 1) * 16384 + w * 4096;
      #pragma unroll
      for (int j = 0; j < 4; ++j) {
        gld16(A + abase + (size_t)j * 8 * K + k1, ad + j * 1024);
        gld16(B + bbase + (size_t)j * 8 * K + k1, bd + j * 1024);
      }
      asm volatile("s_waitcnt vmcnt(8)" ::: "memory");
    } else {
      asm volatile("s_waitcnt vmcnt(0)" ::: "memory");
    }
    __builtin_amdgcn_s_barrier();
    const char* ab = aB + cur * 16384;
    const char* bb = bB + cur * 16384;
    bf16x8 af[2][4], bfr[2][4];
    #pragma unroll
    for (int kk = 0; kk < 2; ++kk) {
      #pragma unroll
      for (int m = 0; m < 4; ++m)
        af[kk][m] = *(const bf16x8*)(ab + m * 2048 + (((kk * 4 + lg) * 16) ^ rsw));
      #pragma unroll
      for (int n = 0; n < 4; ++n)
        bfr[kk][n] = *(const bf16x8*)(bb + n * 2048 + (((kk * 4 + lg) * 16) ^ rsw));
    }
    #pragma unroll
    for (int kk = 0; kk < 2; ++kk)
      #pragma unroll
      for (int m = 0; m < 4; ++m)
        #pragma unroll
        for (int n = 0; n < 4; ++n)
          acc[m][n] = __builtin_amdgcn_mfma_f32_16x16x32_bf16(af[kk][m], bfr[kk][n], acc[m][n], 0, 0, 0);
    if (t + 1 < T) __builtin_amdgcn_s_barrier();
  }
}

// kv permutation for VT: s bits[4:2] rotated (p4=s3, p3=s2, p2=s4) -> PV's P is lane-local
static __device__ __forceinline__ int kvperm(int s) {
  return (s & ~0x1C) | ((s & 0x0C) << 1) | ((s & 0x10) >> 2);
}

// ---------------- GEMM1: qkv projection, scatter epilogue ----------------
__global__ __launch_bounds__(256) void k_gemm_qkv(
    const unsigned short* __restrict__ Xb, const unsigned short* __restrict__ Wt,
    const float* __restrict__ bias,
    unsigned short* __restrict__ Qb, unsigned short* __restrict__ Kb,
    unsigned short* __restrict__ VTb) {
  __shared__ __align__(16) char Alds[2 * 16384];
  __shared__ __align__(16) char Blds[2 * 16384];
  f32x4 acc[4][4];
  const int bm = blockIdx.x, bn = blockIdx.y;
  gemm_tile_128(Xb, Wt, EMB, bm, bn, Alds, Blds, acc);
  const int tid = threadIdx.x, lane = tid & 63, w = tid >> 6;
  const int l15 = lane & 15, lg = lane >> 4, wm = w >> 1, wn = w & 1;
  const int treg = bn / 6;
  if (treg < 2) {
    #pragma unroll
    for (int m = 0; m < 4; ++m)
      #pragma unroll
      for (int n = 0; n < 4; ++n)
        #pragma unroll
        for (int r = 0; r < 4; ++r) {
          int gr = bm * 128 + wm * 64 + m * 16 + lg * 4 + r;
          int gc = bn * 128 + wn * 64 + n * 16 + l15;
          float v = acc[m][n][r] + bias[gc];
          int rem = gc - treg * 768;
          int h = rem >> 6, d = rem & 63;
          int b = gr >> 11, s = gr & 2047;
          size_t off = ((size_t)(b * 12 + h) * 2048 + s) * 64 + d;
          if (treg == 0) Qb[off] = b16(v * QSCALE);
          else           Kb[off] = b16(v);
        }
  } else {
    #pragma unroll
    for (int m = 0; m < 4; ++m)
      #pragma unroll
      for (int n = 0; n < 4; ++n) {
        int gr0 = bm * 128 + wm * 64 + m * 16 + lg * 4;
        int gc = bn * 128 + wn * 64 + n * 16 + l15;
        int rem = gc - 1536;
        int h = rem >> 6, d = rem & 63;
        int b = gr0 >> 11, s0 = gr0 & 2047;
        int sp0 = kvperm(s0);
        ushortx4 o;
        #pragma unroll
        for (int r = 0; r < 4; ++r) o[r] = b16(acc[m][n][r] + bias[gc]);
        *(ushortx4*)(VTb + ((size_t)(b * 12 + h) * 64 + d) * 2048 + sp0) = o;
      }
  }
}

// ---------------- GEMM2: output projection ----------------
__global__ __launch_bounds__(256) void k_gemm_proj(
    const unsigned short* __restrict__ Ab, const unsigned short* __restrict__ Wt,
    const float* __restrict__ bias, float* __restrict__ out) {
  __shared__ __align__(16) char Alds[2 * 16384];
  __shared__ __align__(16) char Blds[2 * 16384];
  f32x4 acc[4][4];
  const int bm = blockIdx.x, bn = blockIdx.y;
  gemm_tile_128(Ab, Wt, EMB, bm, bn, Alds, Blds, acc);
  const int tid = threadIdx.x, lane = tid & 63, w = tid >> 6;
  const int l15 = lane & 15, lg = lane >> 4, wm = w >> 1, wn = w & 1;
  #pragma unroll
  for (int m = 0; m < 4; ++m)
    #pragma unroll
    for (int n = 0; n < 4; ++n)
      #pragma unroll
      for (int r = 0; r < 4; ++r) {
        int gr = bm * 128 + wm * 64 + m * 16 + lg * 4 + r;
        int gc = bn * 128 + wn * 64 + n * 16 + l15;
        out[(size_t)gr * EMB + gc] = acc[m][n][r] + bias[gc];
      }
}

// ---------------- flash attention: (q-half, kv-half) wave split, 3-buf pipeline ----------------
// Wave (qh=w>>1, kh=w&1): q rows qt*64+qh*32+{n*16+l15}, kv rows kh*32+{n2*16+lg*4+r}.
// sv[n][n2] = S^T over this kv-half; P positions j=n2*4+r match VT kvperm k-map (verified algebra).
// Epilogue: ALL waves write acc+l to carved scratch; partner w^1 halves summed; wave outputs n==kh.
__global__ __launch_bounds__(256) void k_attn(
    const unsigned short* __restrict__ Qg, const unsigned short* __restrict__ Kg,
    const unsigned short* __restrict__ VTg, unsigned short* __restrict__ AO) {
  __shared__ __align__(16) char LDSbuf[49152];   // [0,24576): K 3x8KB | [24576,49152): VT 3x8KB
  char* KL  = LDSbuf;
  char* VTL = LDSbuf + 24576;
  const int bid = blockIdx.x;
  const int slot = bid >> 3;
  const int bh = (bid & 7) * 3 + slot / 32;      // XCD (bid%8) owns 3 consecutive heads
  const int qt = slot & 31;
  const int b = bh / 12, h = bh % 12;
  const size_t base = (size_t)bh * (SEQ * HDIM);
  const int tid = threadIdx.x, lane = tid & 63, w = tid >> 6;
  const int l15 = lane & 15, lg = lane >> 4;
  const int qh = w >> 1, kh = w & 1;
  const int swz = (l15 & 7) << 4;

  // Q B-frags: qf[n][c][j] = Q[qt*64+qh*32+n*16+l15][c*32+lg*8+j]
  bf16x8 qf[2][2];
  {
    const size_t qoff = base + (size_t)(qt * 64 + qh * 32 + l15) * 64 + lg * 8;
    qf[0][0] = *(const bf16x8*)(Qg + qoff);
    qf[0][1] = *(const bf16x8*)(Qg + qoff + 32);
    qf[1][0] = *(const bf16x8*)(Qg + qoff + 1024);
    qf[1][1] = *(const bf16x8*)(Qg + qoff + 1024 + 32);
  }

  const int srow0 = tid >> 3;
  const int scg0 = (tid & 7) ^ (srow0 & 7);
  const int scg1 = (tid & 7) ^ ((srow0 + 32) & 7);

  #define ASTAGE(tt, buf) do {                                                         \
    const int kv_ = (tt) * 64;                                                         \
    char* kd_ = KL + (buf) * 8192 + w * 1024;                                          \
    char* vd_ = VTL + (buf) * 8192 + w * 1024;                                         \
    gld16(Kg + base + (size_t)(kv_ + srow0) * 64 + scg0 * 8,           kd_);           \
    gld16(Kg + base + (size_t)(kv_ + srow0 + 32) * 64 + scg1 * 8,      kd_ + 4096);    \
    gld16(VTg + base + (size_t)srow0 * 2048 + kv_ + scg0 * 8,          vd_);           \
    gld16(VTg + base + (size_t)(srow0 + 32) * 2048 + kv_ + scg1 * 8,   vd_ + 4096);    \
  } while (0)

  f32x4 acc[2][4];   // acc[n][nd]: O^T-half[d=nd*16+lg*4+r][q=qh*32+n*16+l15]
  #pragma unroll
  for (int n = 0; n < 2; ++n)
    #pragma unroll
    for (int nd = 0; nd < 4; ++nd) acc[n][nd] = (f32x4){0.f, 0.f, 0.f, 0.f};
  float lsum[2] = {0.f, 0.f};

  ASTAGE(0, 0);
  ASTAGE(1, 1);
  asm volatile("s_waitcnt vmcnt(4)" ::: "memory");
  __builtin_amdgcn_s_barrier();

  int cur = 0, pre = 2;
  for (int t = 0; t < 32; ++t) {
    if (t + 2 < 32) ASTAGE(t + 2, pre);
    const char* kb = KL + cur * 8192;
    const char* vb = VTL + cur * 8192;

    __builtin_amdgcn_s_setprio(1);
    // fragment reads: this wave's kv-half only (8 x ds_read_b128)
    bf16x8 kf[2][2], vf[4];
    #pragma unroll
    for (int n2 = 0; n2 < 2; ++n2) {
      const char* rb = kb + (kh * 32 + n2 * 16 + l15) * 128;
      kf[n2][0] = *(const bf16x8*)(rb + ((lg * 16) ^ swz));
      kf[n2][1] = *(const bf16x8*)(rb + ((64 + lg * 16) ^ swz));
    }
    #pragma unroll
    for (int nd = 0; nd < 4; ++nd)
      vf[nd] = *(const bf16x8*)(vb + (nd * 16 + l15) * 128 + ((kh * 64 + lg * 16) ^ swz));

    // S^T for both q-sets over this kv-half
    f32x4 sv[2][2];
    #pragma unroll
    for (int n = 0; n < 2; ++n)
      #pragma unroll
      for (int n2 = 0; n2 < 2; ++n2) {
        f32x4 z = (f32x4){0.f, 0.f, 0.f, 0.f};
        z = __builtin_amdgcn_mfma_f32_16x16x32_bf16(kf[n2][0], qf[n][0], z, 0, 0, 0);
        sv[n][n2] = __builtin_amdgcn_mfma_f32_16x16x32_bf16(kf[n2][1], qf[n][1], z, 0, 0, 0);
      }

    // P = exp2(S) -> pf[n] (B-frag j = n2*4 + r), PV
    #pragma unroll
    for (int n = 0; n < 2; ++n) {
      float p0 = __builtin_amdgcn_exp2f(sv[n][0][0]);
      float p1 = __builtin_amdgcn_exp2f(sv[n][0][1]);
      float p2 = __builtin_amdgcn_exp2f(sv[n][0][2]);
      float p3 = __builtin_amdgcn_exp2f(sv[n][0][3]);
      float p4 = __builtin_amdgcn_exp2f(sv[n][1][0]);
      float p5 = __builtin_amdgcn_exp2f(sv[n][1][1]);
      float p6 = __builtin_amdgcn_exp2f(sv[n][1][2]);
      float p7 = __builtin_amdgcn_exp2f(sv[n][1][3]);
      lsum[n] += ((p0 + p1) + (p2 + p3)) + ((p4 + p5) + (p6 + p7));
      uintx4 uw;
      uw[0] = cvtpk(p0, p1);
      uw[1] = cvtpk(p2, p3);
      uw[2] = cvtpk(p4, p5);
      uw[3] = cvtpk(p6, p7);
      bf16x8 pf = __builtin_bit_cast(bf16x8, uw);
      #pragma unroll
      for (int nd = 0; nd < 4; ++nd)
        acc[n][nd] = __builtin_amdgcn_mfma_f32_16x16x32_bf16(vf[nd], pf, acc[n][nd], 0, 0, 0);
    }
    __builtin_amdgcn_s_setprio(0);

    if (t < 31) {
      if (t < 30) asm volatile("s_waitcnt vmcnt(4)" ::: "memory");
      else        asm volatile("s_waitcnt vmcnt(0)" ::: "memory");
      __builtin_amdgcn_s_barrier();
    }
    cur = (cur == 2) ? 0 : cur + 1;
    pre = (pre == 2) ? 0 : pre + 1;
  }
  #undef ASTAGE

  // ---- epilogue: symmetric cross-wave pairwise reduction via carved scratch ----
  // reduce l over lg groups first (all lanes end up with the full kv-half row-sum)
  #pragma unroll
  for (int n = 0; n < 2; ++n) {
    lsum[n] += __shfl_xor(lsum[n], 16);
    lsum[n] += __shfl_xor(lsum[n], 32);
  }
  __syncthreads();                         // all waves past their final LDS buffer reads
  float* scr = (float*)LDSbuf;             // 8192 floats: [w][n][nd][lane] f32x4
  float* lscr = scr + 8192;                // 128 floats: [w][n][l15]
  #pragma unroll
  for (int n = 0; n < 2; ++n)
    #pragma unroll
    for (int nd = 0; nd < 4; ++nd)
      *(f32x4*)(scr + ((w * 2 + n) * 4 + nd) * 256 + lane * 4) = acc[n][nd];
  if (lane < 16) {
    lscr[w * 32 + l15] = lsum[0];
    lscr[w * 32 + 16 + l15] = lsum[1];
  }
  __syncthreads();
  {
    const int pw = w ^ 1;                  // partner wave: same qh, other kv-half
    const int n = kh;                      // this wave outputs q-set n == kh
    const float lp = lscr[pw * 32 + n * 16 + l15];
    const float rl = 1.0f / (lsum[n] + lp);
    const int q = qt * 64 + qh * 32 + n * 16 + l15;
    unsigned short* aor = AO + ((size_t)(b * 2048 + q)) * EMB + h * 64;
    #pragma unroll
    for (int nd = 0; nd < 4; ++nd) {
      f32x4 part = *(const f32x4*)(scr + ((pw * 2 + n) * 4 + nd) * 256 + lane * 4);
      ushortx4 o;
      #pragma unroll
      for (int r = 0; r < 4; ++r) o[r] = b16((acc[n][nd][r] + part[r]) * rl);
      *(ushortx4*)(aor + nd * 16 + lg * 4) = o;
    }
  }
}

// ---------------- launch ----------------
extern "C" void kernel_launch(void* const* d_in, const int* in_sizes, int n_in,
                              void* d_out, int out_size, void* d_ws, size_t ws_size,
                              hipStream_t stream) {
  const float* x     = (const float*)d_in[0];
  const float* wqkv  = (const float*)d_in[1];
  const float* bqkv  = (const float*)d_in[2];
  const float* wproj = (const float*)d_in[3];
  const float* bproj = (const float*)d_in[4];
  float* out = (float*)d_out;
  char* ws = (char*)d_ws;

  unsigned short* xb     = (unsigned short*)(ws + 0);          // 4096*768*2
  unsigned short* wqkvT  = (unsigned short*)(ws + 6291456);    // 2304*768*2
  unsigned short* wprojT = (unsigned short*)(ws + 9830400);    //  768*768*2
  unsigned short* Qb     = (unsigned short*)(ws + 11010048);   // 24*2048*64*2
  unsigned short* Kb     = (unsigned short*)(ws + 17301504);
  unsigned short* VTb    = (unsigned short*)(ws + 23592960);   // [bh][64][2048] permuted
  unsigned short* AOb    = (unsigned short*)(ws + 29884416);   // 4096*768*2

  k_prep<<<2112, 256, 0, stream>>>(x, wqkv, wproj, xb, wqkvT, wprojT);
  k_gemm_qkv<<<dim3(MROWS / 128, NQKV / 128), 256, 0, stream>>>(xb, wqkvT, bqkv, Qb, Kb, VTb);
  k_attn<<<24 * (SEQ / 64), 256, 0, stream>>>(Qb, Kb, VTb, AOb);
  k_gemm_proj<<<dim3(MROWS / 128, EMB / 128), 256, 0, stream>>>(AOb, wprojT, bproj, out);
}

// Round 18
// 86.813 us; speedup vs baseline: 1.0632x; 1.0632x over previous
//
#include <hip/hip_runtime.h>
#include <hip/hip_bf16.h>

// MHA forward: B=2, S=2048, E=768, H=12, D=64.
// r10 base; GEMM2 retiled 128x128 -> 64x64 (768 blocks = 3/CU), staging in the proven
// wave-uniform global_load_lds form (r17's per-lane LDS dest violated m104 -> fixed).
// k_prep: cvt(x) x8 + transpose+cvt(weights), vectorized stores
// GEMM1 (128x128, BK=64, 2-buf counted-vmcnt, swizzled LDS): qkv -> Q (pre-scaled), K, VT
// k_attn: r10-exact (4 waves x 16 q-rows, swapped QK^T, reg-resident P, 3-buf, XCD-clustered)
// GEMM2 (64x64, BK=64, 2-buf, XCD-chunked): out = AO @ w_proj + b_proj (fp32)

typedef __bf16 bf16x8 __attribute__((ext_vector_type(8)));
typedef float f32x4 __attribute__((ext_vector_type(4)));
typedef unsigned short ushortx8 __attribute__((ext_vector_type(8)));
typedef unsigned short ushortx4 __attribute__((ext_vector_type(4)));

#define EMB 768
#define SEQ 2048
#define NHEAD 12
#define HDIM 64
#define MROWS 4096
#define NQKV 2304
#define QSCALE 0.18033688011112042f   // 0.125 * log2(e)

static __device__ __forceinline__ unsigned short b16(float f) {
  __hip_bfloat16 h = __float2bfloat16(f);
  return __builtin_bit_cast(unsigned short, h);
}

static __device__ __forceinline__ void gld16(const void* g, void* l) {
  __builtin_amdgcn_global_load_lds((const __attribute__((address_space(1))) void*)g,
                                   (__attribute__((address_space(3))) void*)l, 16, 0, 0);
}

// ---------------- fused prep: cvt(x) x8 + transpose+cvt(weights), vectorized stores ----------------
__global__ __launch_bounds__(256) void k_prep(
    const float* __restrict__ x, const float* __restrict__ wqkv, const float* __restrict__ wproj,
    unsigned short* __restrict__ xb, unsigned short* __restrict__ wqkvT,
    unsigned short* __restrict__ wprojT) {
  __shared__ float t[64][65];
  const int bid = blockIdx.x;
  const int tid = threadIdx.x;
  if (bid < 1536) {                       // cvt x: 1536*256*8 = 4096*768
    int i = (bid * 256 + tid) * 8;
    f32x4 v0 = *(const f32x4*)(x + i);
    f32x4 v1 = *(const f32x4*)(x + i + 4);
    ushortx8 o;
    o[0] = b16(v0[0]); o[1] = b16(v0[1]); o[2] = b16(v0[2]); o[3] = b16(v0[3]);
    o[4] = b16(v1[0]); o[5] = b16(v1[1]); o[6] = b16(v1[2]); o[7] = b16(v1[3]);
    *(ushortx8*)(xb + i) = o;
    return;
  }
  const float* in; unsigned short* out; int N, bx, by;
  if (bid < 1536 + 432) { in = wqkv;  out = wqkvT;  N = NQKV; int r = bid - 1536; bx = r % 36; by = r / 36; }
  else                  { in = wproj; out = wprojT; N = EMB;  int r = bid - 1968; bx = r % 12; by = r / 12; }
  const int n0 = bx * 64, k0 = by * 64;
  const int xx = tid & 63, y0 = tid >> 6;
  #pragma unroll
  for (int i = 0; i < 16; ++i) { int r = y0 * 16 + i; t[r][xx] = in[(size_t)(k0 + r) * N + n0 + xx]; }
  __syncthreads();
  const int ks = tid & 7;                 // k-slot (8 bf16 = 16B)
  const int nr0 = tid >> 3;               // n-row 0..31
  #pragma unroll
  for (int i = 0; i < 2; ++i) {
    int nr = nr0 + i * 32;
    ushortx8 o;
    #pragma unroll
    for (int j = 0; j < 8; ++j) o[j] = b16(t[ks * 8 + j][nr]);
    *(ushortx8*)(out + (size_t)(n0 + nr) * EMB + k0 + ks * 8) = o;
  }
}

// ---------------- 128x128 bf16 GEMM mainloop (r7-exact), BK=64, 2-buf, swizzled ----------
static __device__ __forceinline__ void gemm_tile_128(
    const unsigned short* __restrict__ A, const unsigned short* __restrict__ B,
    int K, int bm, int bn, char* lA, char* lB, f32x4 acc[4][4]) {
  const int tid = threadIdx.x, lane = tid & 63, w = tid >> 6;
  const int l15 = lane & 15, lg = lane >> 4;
  const int wm = w >> 1, wn = w & 1;
  #pragma unroll
  for (int m = 0; m < 4; ++m)
    #pragma unroll
    for (int n = 0; n < 4; ++n)
      acc[m][n] = (f32x4){0.f, 0.f, 0.f, 0.f};

  const int srow = w * 32 + (lane >> 3);
  const int glog = (lane & 7) ^ (lane >> 3);
  const size_t abase = (size_t)(bm * 128 + srow) * K + glog * 8;
  const size_t bbase = (size_t)(bn * 128 + srow) * K + glog * 8;
  const char* aB = lA + (wm * 64 + l15) * 128;
  const char* bB = lB + (wn * 64 + l15) * 128;
  const int rsw = (l15 & 7) << 4;

  const int T = K >> 6;
  {
    char* ad = lA + w * 4096; char* bd = lB + w * 4096;
    #pragma unroll
    for (int j = 0; j < 4; ++j) {
      gld16(A + abase + (size_t)j * 8 * K, ad + j * 1024);
      gld16(B + bbase + (size_t)j * 8 * K, bd + j * 1024);
    }
  }
  for (int t = 0; t < T; ++t) {
    const int cur = t & 1;
    if (t + 1 < T) {
      const int k1 = (t + 1) << 6;
      char* ad = lA + (cur ^ 1) * 16384 + w * 4096;
      char* bd = lB + (cur ^ 1) * 16384 + w * 4096;
      #pragma unroll
      for (int j = 0; j < 4; ++j) {
        gld16(A + abase + (size_t)j * 8 * K + k1, ad + j * 1024);
        gld16(B + bbase + (size_t)j * 8 * K + k1, bd + j * 1024);
      }
      asm volatile("s_waitcnt vmcnt(8)" ::: "memory");
    } else {
      asm volatile("s_waitcnt vmcnt(0)" ::: "memory");
    }
    __builtin_amdgcn_s_barrier();
    const char* ab = aB + cur * 16384;
    const char* bb = bB + cur * 16384;
    bf16x8 af[2][4], bfr[2][4];
    #pragma unroll
    for (int kk = 0; kk < 2; ++kk) {
      #pragma unroll
      for (int m = 0; m < 4; ++m)
        af[kk][m] = *(const bf16x8*)(ab + m * 2048 + (((kk * 4 + lg) * 16) ^ rsw));
      #pragma unroll
      for (int n = 0; n < 4; ++n)
        bfr[kk][n] = *(const bf16x8*)(bb + n * 2048 + (((kk * 4 + lg) * 16) ^ rsw));
    }
    #pragma unroll
    for (int kk = 0; kk < 2; ++kk)
      #pragma unroll
      for (int m = 0; m < 4; ++m)
        #pragma unroll
        for (int n = 0; n < 4; ++n)
          acc[m][n] = __builtin_amdgcn_mfma_f32_16x16x32_bf16(af[kk][m], bfr[kk][n], acc[m][n], 0, 0, 0);
    if (t + 1 < T) __builtin_amdgcn_s_barrier();
  }
}

// kv permutation for VT: s bits[4:2] rotated (p4=s3, p3=s2, p2=s4) -> PV's P is lane-local
static __device__ __forceinline__ int kvperm(int s) {
  return (s & ~0x1C) | ((s & 0x0C) << 1) | ((s & 0x10) >> 2);
}

// ---------------- GEMM1: qkv projection, scatter epilogue ----------------
__global__ __launch_bounds__(256) void k_gemm_qkv(
    const unsigned short* __restrict__ Xb, const unsigned short* __restrict__ Wt,
    const float* __restrict__ bias,
    unsigned short* __restrict__ Qb, unsigned short* __restrict__ Kb,
    unsigned short* __restrict__ VTb) {
  __shared__ __align__(16) char Alds[2 * 16384];
  __shared__ __align__(16) char Blds[2 * 16384];
  f32x4 acc[4][4];
  const int bm = blockIdx.x, bn = blockIdx.y;
  gemm_tile_128(Xb, Wt, EMB, bm, bn, Alds, Blds, acc);
  const int tid = threadIdx.x, lane = tid & 63, w = tid >> 6;
  const int l15 = lane & 15, lg = lane >> 4, wm = w >> 1, wn = w & 1;
  const int treg = bn / 6;   // block-uniform region: 0=Q, 1=K, 2=V
  if (treg < 2) {
    #pragma unroll
    for (int m = 0; m < 4; ++m)
      #pragma unroll
      for (int n = 0; n < 4; ++n)
        #pragma unroll
        for (int r = 0; r < 4; ++r) {
          int gr = bm * 128 + wm * 64 + m * 16 + lg * 4 + r;
          int gc = bn * 128 + wn * 64 + n * 16 + l15;
          float v = acc[m][n][r] + bias[gc];
          int rem = gc - treg * 768;
          int h = rem >> 6, d = rem & 63;
          int b = gr >> 11, s = gr & 2047;
          size_t off = ((size_t)(b * 12 + h) * 2048 + s) * 64 + d;
          if (treg == 0) Qb[off] = b16(v * QSCALE);
          else           Kb[off] = b16(v);
        }
  } else {
    #pragma unroll
    for (int m = 0; m < 4; ++m)
      #pragma unroll
      for (int n = 0; n < 4; ++n) {
        int gr0 = bm * 128 + wm * 64 + m * 16 + lg * 4;
        int gc = bn * 128 + wn * 64 + n * 16 + l15;
        int rem = gc - 1536;
        int h = rem >> 6, d = rem & 63;
        int b = gr0 >> 11, s0 = gr0 & 2047;
        int sp0 = kvperm(s0);                   // bits[1:0] preserved
        ushortx4 o;
        #pragma unroll
        for (int r = 0; r < 4; ++r) o[r] = b16(acc[m][n][r] + bias[gc]);
        *(ushortx4*)(VTb + ((size_t)(b * 12 + h) * 64 + d) * 2048 + sp0) = o;
      }
  }
}

// ---------------- GEMM2: 64x64 tiles, XCD-chunked grid, wave-uniform staging ----------------
// Grid 768 blocks (= 3/CU). XCD x = id&7 owns bm in [8x, 8x+8) x all 12 bn.
// Staging (r7 pattern scaled): wave w stages rows w*8+(lane>>3) and +32, dest wave-uniform
// lA+buf*8192+w*1024 (+4096); source granule glog=(lane&7)^(lane>>3). 4 loads/thread/step.
__global__ __launch_bounds__(256) void k_gemm_proj(
    const unsigned short* __restrict__ Ab, const unsigned short* __restrict__ Wt,
    const float* __restrict__ bias, float* __restrict__ out) {
  __shared__ __align__(16) char Alds[2 * 8192];
  __shared__ __align__(16) char Blds[2 * 8192];
  const int id = blockIdx.x;               // 768 blocks
  const int k = id >> 3;                   // 0..95
  const int bn = k % 12;
  const int bm = (id & 7) * 8 + k / 12;
  const int tid = threadIdx.x, lane = tid & 63, w = tid >> 6;
  const int l15 = lane & 15, lg = lane >> 4;
  const int wm = w >> 1, wn = w & 1;
  f32x4 acc[2][2];
  #pragma unroll
  for (int m = 0; m < 2; ++m)
    #pragma unroll
    for (int n = 0; n < 2; ++n)
      acc[m][n] = (f32x4){0.f, 0.f, 0.f, 0.f};

  const int srow = w * 8 + (lane >> 3);              // rows 0..31; +32 for second half
  const int glog = (lane & 7) ^ (lane >> 3);         // pre-swizzled source granule
  const size_t abase  = (size_t)(bm * 64 + srow) * EMB + glog * 8;
  const size_t abase2 = abase + (size_t)32 * EMB;
  const size_t bbase  = (size_t)(bn * 64 + srow) * EMB + glog * 8;
  const size_t bbase2 = bbase + (size_t)32 * EMB;
  const char* aB = (char*)Alds + (wm * 32 + l15) * 128;
  const char* bB = (char*)Blds + (wn * 32 + l15) * 128;
  const int rsw = (l15 & 7) << 4;

  #define G2STAGE(k1, buf) do {                                          \
    char* ad_ = (char*)Alds + (buf) * 8192 + w * 1024;                   \
    char* bd_ = (char*)Blds + (buf) * 8192 + w * 1024;                   \
    gld16(Ab + abase + (k1), ad_);                                       \
    gld16(Ab + abase2 + (k1), ad_ + 4096);                               \
    gld16(Wt + bbase + (k1), bd_);                                       \
    gld16(Wt + bbase2 + (k1), bd_ + 4096);                               \
  } while (0)

  G2STAGE(0, 0);
  const int T = EMB >> 6;   // 12
  for (int t = 0; t < T; ++t) {
    const int cur = t & 1;
    if (t + 1 < T) {
      G2STAGE((t + 1) << 6, cur ^ 1);
      asm volatile("s_waitcnt vmcnt(4)" ::: "memory");
    } else {
      asm volatile("s_waitcnt vmcnt(0)" ::: "memory");
    }
    __builtin_amdgcn_s_barrier();
    const char* ab = aB + cur * 8192;
    const char* bb = bB + cur * 8192;
    bf16x8 af[2][2], bfr[2][2];
    #pragma unroll
    for (int kk = 0; kk < 2; ++kk) {
      #pragma unroll
      for (int m = 0; m < 2; ++m)
        af[kk][m] = *(const bf16x8*)(ab + m * 2048 + (((kk * 4 + lg) * 16) ^ rsw));
      #pragma unroll
      for (int n = 0; n < 2; ++n)
        bfr[kk][n] = *(const bf16x8*)(bb + n * 2048 + (((kk * 4 + lg) * 16) ^ rsw));
    }
    #pragma unroll
    for (int kk = 0; kk < 2; ++kk)
      #pragma unroll
      for (int m = 0; m < 2; ++m)
        #pragma unroll
        for (int n = 0; n < 2; ++n)
          acc[m][n] = __builtin_amdgcn_mfma_f32_16x16x32_bf16(af[kk][m], bfr[kk][n], acc[m][n], 0, 0, 0);
    if (t + 1 < T) __builtin_amdgcn_s_barrier();
  }
  #undef G2STAGE

  #pragma unroll
  for (int m = 0; m < 2; ++m)
    #pragma unroll
    for (int n = 0; n < 2; ++n)
      #pragma unroll
      for (int r = 0; r < 4; ++r) {
        int gr = bm * 64 + wm * 32 + m * 16 + lg * 4 + r;
        int gc = bn * 64 + wn * 32 + n * 16 + l15;
        out[(size_t)gr * EMB + gc] = acc[m][n][r] + bias[gc];
      }
}

// ---------------- flash attention per (b,h), 64-row q-tiles, 3-buffer pipeline (r10-exact) ----
__global__ __launch_bounds__(256) void k_attn(
    const unsigned short* __restrict__ Qg, const unsigned short* __restrict__ Kg,
    const unsigned short* __restrict__ VTg, unsigned short* __restrict__ AO) {
  __shared__ __align__(16) char KL[3 * 8192];
  __shared__ __align__(16) char VTL[3 * 8192];
  const int bid = blockIdx.x;
  const int slot = bid >> 3;
  const int bh = (bid & 7) * 3 + slot / 32;      // XCD (bid%8) owns 3 consecutive heads
  const int qt = slot & 31;
  const int b = bh / 12, h = bh % 12;
  const size_t base = (size_t)bh * (SEQ * HDIM);
  const int tid = threadIdx.x, lane = tid & 63, w = tid >> 6;
  const int l15 = lane & 15, lg = lane >> 4;
  const int swz = (l15 & 7) << 4;

  bf16x8 qf[2];
  {
    const size_t qoff = base + (size_t)(qt * 64 + w * 16 + l15) * 64 + lg * 8;
    qf[0] = *(const bf16x8*)(Qg + qoff);
    qf[1] = *(const bf16x8*)(Qg + qoff + 32);
  }

  const int srow0 = tid >> 3;
  const int scg0 = (tid & 7) ^ (srow0 & 7);
  const int scg1 = (tid & 7) ^ ((srow0 + 32) & 7);

  #define ASTAGE(tt, buf) do {                                                         \
    const int kv_ = (tt) * 64;                                                         \
    char* kd_ = KL + (buf) * 8192 + w * 1024;                                          \
    char* vd_ = VTL + (buf) * 8192 + w * 1024;                                         \
    gld16(Kg + base + (size_t)(kv_ + srow0) * 64 + scg0 * 8,           kd_);           \
    gld16(Kg + base + (size_t)(kv_ + srow0 + 32) * 64 + scg1 * 8,      kd_ + 4096);    \
    gld16(VTg + base + (size_t)srow0 * 2048 + kv_ + scg0 * 8,          vd_);           \
    gld16(VTg + base + (size_t)(srow0 + 32) * 2048 + kv_ + scg1 * 8,   vd_ + 4096);    \
  } while (0)

  f32x4 Oacc[4];
  #pragma unroll
  for (int nd = 0; nd < 4; ++nd) Oacc[nd] = (f32x4){0.f, 0.f, 0.f, 0.f};
  float l_ = 0.f;

  ASTAGE(0, 0);
  ASTAGE(1, 1);
  asm volatile("s_waitcnt vmcnt(4)" ::: "memory");
  __builtin_amdgcn_s_barrier();

  int cur = 0, pre = 2;
  for (int t = 0; t < 32; ++t) {
    if (t + 2 < 32) ASTAGE(t + 2, pre);
    const char* kb = KL + cur * 8192;
    const char* vb = VTL + cur * 8192;

    f32x4 sv[4];
    __builtin_amdgcn_s_setprio(1);
    #pragma unroll
    for (int n = 0; n < 4; ++n) {
      const char* rb = kb + (n * 16 + l15) * 128;
      bf16x8 kf0 = *(const bf16x8*)(rb + ((lg * 16) ^ swz));
      bf16x8 kf1 = *(const bf16x8*)(rb + ((64 + lg * 16) ^ swz));
      f32x4 z = (f32x4){0.f, 0.f, 0.f, 0.f};
      z = __builtin_amdgcn_mfma_f32_16x16x32_bf16(kf0, qf[0], z, 0, 0, 0);
      sv[n] = __builtin_amdgcn_mfma_f32_16x16x32_bf16(kf1, qf[1], z, 0, 0, 0);
    }

    #pragma unroll
    for (int c = 0; c < 2; ++c) {
      ushortx8 up;
      #pragma unroll
      for (int j = 0; j < 4; ++j) {
        float pa = __builtin_amdgcn_exp2f(sv[2 * c][j]);
        float pb = __builtin_amdgcn_exp2f(sv[2 * c + 1][j]);
        l_ += pa + pb;
        up[j] = b16(pa);
        up[4 + j] = b16(pb);
      }
      bf16x8 pfB = __builtin_bit_cast(bf16x8, up);
      #pragma unroll
      for (int nd = 0; nd < 4; ++nd) {
        const char* vr = vb + (nd * 16 + l15) * 128;
        bf16x8 vf = *(const bf16x8*)(vr + ((c * 64 + lg * 16) ^ swz));
        Oacc[nd] = __builtin_amdgcn_mfma_f32_16x16x32_bf16(vf, pfB, Oacc[nd], 0, 0, 0);
      }
    }
    __builtin_amdgcn_s_setprio(0);

    if (t < 31) {
      if (t < 30) asm volatile("s_waitcnt vmcnt(4)" ::: "memory");
      else        asm volatile("s_waitcnt vmcnt(0)" ::: "memory");
      __builtin_amdgcn_s_barrier();
    }
    cur = (cur == 2) ? 0 : cur + 1;
    pre = (pre == 2) ? 0 : pre + 1;
  }
  #undef ASTAGE

  // ---- epilogue: reduce l across lg groups, normalize, vectorized O^T store ----
  l_ += __shfl_xor(l_, 16);
  l_ += __shfl_xor(l_, 32);
  const float rl = 1.0f / l_;
  const int q = qt * 64 + w * 16 + l15;
  #pragma unroll
  for (int nd = 0; nd < 4; ++nd) {
    ushortx4 o;
    #pragma unroll
    for (int r = 0; r < 4; ++r) o[r] = b16(Oacc[nd][r] * rl);
    *(ushortx4*)(AO + ((size_t)(b * 2048 + q)) * EMB + h * 64 + nd * 16 + lg * 4) = o;
  }
}

// ---------------- launch ----------------
extern "C" void kernel_launch(void* const* d_in, const int* in_sizes, int n_in,
                              void* d_out, int out_size, void* d_ws, size_t ws_size,
                              hipStream_t stream) {
  const float* x     = (const float*)d_in[0];
  const float* wqkv  = (const float*)d_in[1];
  const float* bqkv  = (const float*)d_in[2];
  const float* wproj = (const float*)d_in[3];
  const float* bproj = (const float*)d_in[4];
  float* out = (float*)d_out;
  char* ws = (char*)d_ws;

  unsigned short* xb     = (unsigned short*)(ws + 0);          // 4096*768*2
  unsigned short* wqkvT  = (unsigned short*)(ws + 6291456);    // 2304*768*2
  unsigned short* wprojT = (unsigned short*)(ws + 9830400);    //  768*768*2
  unsigned short* Qb     = (unsigned short*)(ws + 11010048);   // 24*2048*64*2
  unsigned short* Kb     = (unsigned short*)(ws + 17301504);
  unsigned short* VTb    = (unsigned short*)(ws + 23592960);   // [bh][64][2048] permuted
  unsigned short* AOb    = (unsigned short*)(ws + 29884416);   // 4096*768*2

  k_prep<<<2112, 256, 0, stream>>>(x, wqkv, wproj, xb, wqkvT, wprojT);
  k_gemm_qkv<<<dim3(MROWS / 128, NQKV / 128), 256, 0, stream>>>(xb, wqkvT, bqkv, Qb, Kb, VTb);
  k_attn<<<24 * (SEQ / 64), 256, 0, stream>>>(Qb, Kb, VTb, AOb);
  k_gemm_proj<<<768, 256, 0, stream>>>(AOb, wprojT, bproj, out);
}